// Round 1
// baseline (265.655 us; speedup 1.0000x reference)
//
#include <hip/hip_runtime.h>
#include <cstddef>

// Problem constants (match reference)
#define B_   256
#define T_   2048
#define DIM_ 64
#define NC_  16              // chunks per row
#define CS_  (T_ / NC_)      // 128 steps per chunk
#define SG_  16              // step-subgroups per block (256 threads / 16 dim-quads)
#define SPS_ (CS_ / SG_)     // 8 steps per subgroup -> 8 float4 in registers/thread
// THETA=0.1, MU=0, SIGMA=1 ; sigma/sqrt(2*theta) = sqrt(5)
#define OU_SCALE 2.2360679774997896f

// delta coefficients for step t of row b:
//  x: brownian-increment std (0 if invalid), y: OU-increment std * sqrt(5)
__device__ __forceinline__ float2 delta_pair(const float* __restrict__ tsb, int t) {
    float tk = tsb[t];
    float tp = (t == 0) ? 0.0f : tsb[t - 1];
    float dt = tk - tp;
    float db  = sqrtf(dt);
    // exp(2θ tk) - exp(2θ tp) = exp(2θ tp) * expm1(2θ dt)
    float dou = sqrtf(expf(0.2f * tp) * expm1f(0.2f * dt));
    float cb = (db  <= 0.0f) ? 0.0f : db;
    float co = (dou <= 0.0f) ? 0.0f : dou * OU_SCALE;
    return make_float2(cb, co);
}

// ---------------------------------------------------------------------------
// Kernel 1: per-chunk weighted partial sums.
// Grid = B*NC blocks of 256 threads. Block (b,c) reads its 128x64 chunk once
// (float4, coalesced), weights by delta, reduces over steps, writes 64 floats.
__global__ __launch_bounds__(256) void partial_kernel(
        const float* __restrict__ ts,
        const float* __restrict__ noise,
        float* __restrict__ partials)
{
    __shared__ float2 dlt[CS_];        // 1 KB
    __shared__ float4 red[SG_][16];    // 4 KB

    const int v   = blockIdx.x;
    const int b   = v >> 4;            // v / NC_
    const int c   = v & (NC_ - 1);
    const int tid = threadIdx.x;
    const int sg  = tid >> 4;          // step subgroup 0..15 (8 contiguous steps)
    const int qi  = tid & 15;          // dim quad index
    const int q   = qi << 2;           // dim base (quad stays within one half)
    const int t0  = c * CS_;

    // Issue the chunk loads first; they stay in flight under the
    // transcendental coef computation (barrier drains them anyway).
    const size_t rowbase = (size_t)b * T_ * DIM_;
    const float* np = noise + rowbase + (size_t)(t0 + sg * SPS_) * DIM_ + q;
    float4 r[SPS_];
#pragma unroll
    for (int i = 0; i < SPS_; ++i)
        r[i] = *(const float4*)(np + (size_t)i * DIM_);

    const float* tsb = ts + (size_t)b * T_;
    if (tid < CS_) dlt[tid] = delta_pair(tsb, t0 + tid);
    __syncthreads();

    const bool ou = q >= (DIM_ / 2);
    float4 a = make_float4(0.f, 0.f, 0.f, 0.f);
#pragma unroll
    for (int i = 0; i < SPS_; ++i) {
        float2 d2 = dlt[sg * SPS_ + i];
        float d = ou ? d2.y : d2.x;
        a.x = fmaf(d, r[i].x, a.x);
        a.y = fmaf(d, r[i].y, a.y);
        a.z = fmaf(d, r[i].z, a.z);
        a.w = fmaf(d, r[i].w, a.w);
    }
    red[sg][qi] = a;
    __syncthreads();

    if (tid < 16) {
        float4 s = red[0][tid];
#pragma unroll
        for (int k = 1; k < SG_; ++k) {
            float4 t4 = red[k][tid];
            s.x += t4.x; s.y += t4.y; s.z += t4.z; s.w += t4.w;
        }
        *(float4*)(partials + ((size_t)b * NC_ + c) * DIM_ + (tid << 2)) = s;
    }
}

// ---------------------------------------------------------------------------
// Kernel 2: cross-chunk base + intra-chunk scan + normalized write.
// Grid = B*NC blocks of 256 threads. Chunk data lives in registers (one read,
// L3-hot from kernel 1); base comes from kernel-1 partials; subgroup prefix
// via 4 KB LDS; float4 stores.
__global__ __launch_bounds__(256) void scan_kernel(
        const float* __restrict__ ts,
        const float* __restrict__ noise,
        const float* __restrict__ partials,
        float* __restrict__ out)
{
    __shared__ float4 cof[CS_];        // {d_bm, d_ou*sqrt5, f_bm, f_ou} 2 KB
    __shared__ float4 red[SG_][16];    // 4 KB

    const int v   = blockIdx.x;
    const int b   = v >> 4;
    const int c   = v & (NC_ - 1);
    const int tid = threadIdx.x;
    const int sg  = tid >> 4;
    const int qi  = tid & 15;
    const int q   = qi << 2;
    const int t0  = c * CS_;

    const size_t rowbase = (size_t)b * T_ * DIM_;
    const float* np = noise + rowbase + (size_t)(t0 + sg * SPS_) * DIM_ + q;
    float4 r[SPS_];
#pragma unroll
    for (int i = 0; i < SPS_; ++i)
        r[i] = *(const float4*)(np + (size_t)i * DIM_);

    // cross-chunk exclusive base from kernel-1 partials (L2-hot, 256 B/iter)
    float4 base = make_float4(0.f, 0.f, 0.f, 0.f);
    const float* pb = partials + (size_t)b * NC_ * DIM_ + q;
    for (int k = 0; k < c; ++k) {
        float4 p = *(const float4*)(pb + k * DIM_);
        base.x += p.x; base.y += p.y; base.z += p.z; base.w += p.w;
    }

    const float* tsb = ts + (size_t)b * T_;
    if (tid < CS_) {
        int t = t0 + tid;
        float2 d  = delta_pair(tsb, t);
        float tk  = tsb[t];
        float fb  = 1.0f / (sqrtf(tk) + 1e-8f);
        float em  = expf(-0.1f * tk);                      // exp(-θ t)
        float fo  = em / (sqrtf(-expm1f(-0.2f * tk) * 5.0f) + 1e-8f);
        cof[t - t0] = make_float4(d.x, d.y, fb, fo);
    }
    __syncthreads();

    // weight in place, accumulate subgroup partial
    const bool ou = q >= (DIM_ / 2);
    float4 s = make_float4(0.f, 0.f, 0.f, 0.f);
#pragma unroll
    for (int i = 0; i < SPS_; ++i) {
        float4 cc = cof[sg * SPS_ + i];
        float d = ou ? cc.y : cc.x;
        r[i].x *= d; r[i].y *= d; r[i].z *= d; r[i].w *= d;
        s.x += r[i].x; s.y += r[i].y; s.z += r[i].z; s.w += r[i].w;
    }
    red[sg][qi] = s;
    __syncthreads();

    // exclusive prefix over earlier subgroups of this chunk
    float4 acc = base;
    for (int k = 0; k < sg; ++k) {
        float4 p = red[k][qi];
        acc.x += p.x; acc.y += p.y; acc.z += p.z; acc.w += p.w;
    }

    // replay from registers, apply per-step normalization, float4 store
    float* op = out + rowbase + (size_t)(t0 + sg * SPS_) * DIM_ + q;
#pragma unroll
    for (int i = 0; i < SPS_; ++i) {
        float4 cc = cof[sg * SPS_ + i];
        float f = ou ? cc.w : cc.z;
        acc.x += r[i].x; acc.y += r[i].y; acc.z += r[i].z; acc.w += r[i].w;
        float4 o = make_float4(acc.x * f, acc.y * f, acc.z * f, acc.w * f);
        *(float4*)(op + (size_t)i * DIM_) = o;
    }
}

// ---------------------------------------------------------------------------
extern "C" void kernel_launch(void* const* d_in, const int* in_sizes, int n_in,
                              void* d_out, int out_size, void* d_ws, size_t ws_size,
                              hipStream_t stream) {
    const float* ts    = (const float*)d_in[0];   // [B,T,1] fp32
    const float* noise = (const float*)d_in[1];   // [B,T,DIM] fp32
    float* out = (float*)d_out;                   // [B,T,DIM] fp32
    // workspace: chunk partials, B*NC*DIM floats = 1 MB (deterministically
    // overwritten by kernel 1 each run — no reset needed, graph-capture safe)
    float* partials = (float*)d_ws;
    (void)ws_size; (void)in_sizes; (void)n_in; (void)out_size;

    partial_kernel<<<B_ * NC_, 256, 0, stream>>>(ts, noise, partials);
    scan_kernel   <<<B_ * NC_, 256, 0, stream>>>(ts, noise, partials, out);
}

// Round 2
// 253.594 us; speedup vs baseline: 1.0476x; 1.0476x over previous
//
#include <hip/hip_runtime.h>
#include <cstddef>

// Problem constants (match reference)
#define B_   256
#define T_   2048
#define DIM_ 64
#define NC_  16              // chunks per row
#define CS_  (T_ / NC_)      // 128 steps per chunk
#define SG_  16              // step-subgroups per block (256 threads / 16 dim-quads)
#define SPS_ (CS_ / SG_)     // 8 steps per subgroup -> 8 float4 in registers/thread
// THETA=0.1, MU=0, SIGMA=1 ; sigma/sqrt(2*theta) = sqrt(5)
#define OU_SCALE 2.2360679774997896f

// delta coefficients for step t of row b:
//  x: brownian-increment std (0 if invalid), y: OU-increment std * sqrt(5)
__device__ __forceinline__ float2 delta_pair(const float* __restrict__ tsb, int t) {
    float tk = tsb[t];
    float tp = (t == 0) ? 0.0f : tsb[t - 1];
    float dt = tk - tp;
    float db  = sqrtf(dt);
    // exp(2θ tk) - exp(2θ tp) = exp(2θ tp) * expm1(2θ dt)
    float dou = sqrtf(expf(0.2f * tp) * expm1f(0.2f * dt));
    float cb = (db  <= 0.0f) ? 0.0f : db;
    float co = (dou <= 0.0f) ? 0.0f : dou * OU_SCALE;
    return make_float2(cb, co);
}

// ---------------------------------------------------------------------------
// Kernel 1: per-chunk weighted partial sums, stashed INSIDE out.
// Block (b,c) reads its 128x64 noise chunk once (float4, coalesced), weights
// by delta, reduces over steps, writes the 64-float partial to
// out[b, c*CS, 0:64] — the head row of its own chunk's output region.
// (No workspace: using d_ws triggers a 512 MiB re-poison fill = +80 us.)
__global__ __launch_bounds__(256) void partial_kernel(
        const float* __restrict__ ts,
        const float* __restrict__ noise,
        float* __restrict__ out)
{
    __shared__ float2 dlt[CS_];        // 1 KB
    __shared__ float4 red[SG_][16];    // 4 KB

    const int v   = blockIdx.x;
    const int b   = v >> 4;            // v / NC_
    const int c   = v & (NC_ - 1);
    const int tid = threadIdx.x;
    const int sg  = tid >> 4;          // step subgroup 0..15 (8 contiguous steps)
    const int qi  = tid & 15;          // dim quad index
    const int q   = qi << 2;           // dim base (quad stays within one half)
    const int t0  = c * CS_;

    // Issue the chunk loads first; they stay in flight under the
    // transcendental coef computation (barrier drains them anyway).
    const size_t rowbase = (size_t)b * T_ * DIM_;
    const float* np = noise + rowbase + (size_t)(t0 + sg * SPS_) * DIM_ + q;
    float4 r[SPS_];
#pragma unroll
    for (int i = 0; i < SPS_; ++i)
        r[i] = *(const float4*)(np + (size_t)i * DIM_);

    const float* tsb = ts + (size_t)b * T_;
    if (tid < CS_) dlt[tid] = delta_pair(tsb, t0 + tid);
    __syncthreads();

    const bool ou = q >= (DIM_ / 2);
    float4 a = make_float4(0.f, 0.f, 0.f, 0.f);
#pragma unroll
    for (int i = 0; i < SPS_; ++i) {
        float2 d2 = dlt[sg * SPS_ + i];
        float d = ou ? d2.y : d2.x;
        a.x = fmaf(d, r[i].x, a.x);
        a.y = fmaf(d, r[i].y, a.y);
        a.z = fmaf(d, r[i].z, a.z);
        a.w = fmaf(d, r[i].w, a.w);
    }
    red[sg][qi] = a;
    __syncthreads();

    if (tid < 16) {
        float4 s = red[0][tid];
#pragma unroll
        for (int k = 1; k < SG_; ++k) {
            float4 t4 = red[k][tid];
            s.x += t4.x; s.y += t4.y; s.z += t4.z; s.w += t4.w;
        }
        *(float4*)(out + rowbase + (size_t)t0 * DIM_ + (tid << 2)) = s;
    }
}

// ---------------------------------------------------------------------------
// Kernel 2: per-row in-place exclusive prefix over the 16 stashed partials.
// After this, out[b, c*CS, l] holds the BASE (sum of chunks < c) for chunk c.
// Tiny: 1 MB read + 1 MB write, L2-hot from kernel 1.
__global__ __launch_bounds__(64) void prefix_kernel(float* __restrict__ out)
{
    const int b = blockIdx.x;
    const int l = threadIdx.x;          // dim 0..63, coalesced
    float* p = out + (size_t)b * T_ * DIM_ + l;
    float acc = 0.0f;
#pragma unroll
    for (int c = 0; c < NC_; ++c) {
        const size_t idx = (size_t)c * CS_ * DIM_;
        float v = p[idx];
        p[idx] = acc;
        acc += v;
    }
}

// ---------------------------------------------------------------------------
// Kernel 3: block (b,c) reads its base from ITS OWN output head-row (before
// the block's first barrier; stores only happen after the second barrier, so
// no cross-block ordering is required), re-reads its noise chunk (L3-hot),
// scans, normalizes, float4 stores.
__global__ __launch_bounds__(256) void scan_kernel(
        const float* __restrict__ ts,
        const float* __restrict__ noise,
        float* __restrict__ out)
{
    __shared__ float4 cof[CS_];        // {d_bm, d_ou*sqrt5, f_bm, f_ou} 2 KB
    __shared__ float4 red[SG_][16];    // 4 KB

    const int v   = blockIdx.x;
    const int b   = v >> 4;
    const int c   = v & (NC_ - 1);
    const int tid = threadIdx.x;
    const int sg  = tid >> 4;
    const int qi  = tid & 15;
    const int q   = qi << 2;
    const int t0  = c * CS_;

    const size_t rowbase = (size_t)b * T_ * DIM_;
    const float* np = noise + rowbase + (size_t)(t0 + sg * SPS_) * DIM_ + q;
    float4 r[SPS_];
#pragma unroll
    for (int i = 0; i < SPS_; ++i)
        r[i] = *(const float4*)(np + (size_t)i * DIM_);

    // cross-chunk base from this block's own stash slot (written by K1+K2)
    float4 base = *(const float4*)(out + rowbase + (size_t)t0 * DIM_ + q);

    const float* tsb = ts + (size_t)b * T_;
    if (tid < CS_) {
        int t = t0 + tid;
        float2 d  = delta_pair(tsb, t);
        float tk  = tsb[t];
        float fb  = 1.0f / (sqrtf(tk) + 1e-8f);
        float em  = expf(-0.1f * tk);                      // exp(-θ t)
        float fo  = em / (sqrtf(-expm1f(-0.2f * tk) * 5.0f) + 1e-8f);
        cof[tid] = make_float4(d.x, d.y, fb, fo);
    }
    __syncthreads();   // also guarantees every thread's base-read precedes any store

    // weight in place, accumulate subgroup partial
    const bool ou = q >= (DIM_ / 2);
    float4 s = make_float4(0.f, 0.f, 0.f, 0.f);
#pragma unroll
    for (int i = 0; i < SPS_; ++i) {
        float4 cc = cof[sg * SPS_ + i];
        float d = ou ? cc.y : cc.x;
        r[i].x *= d; r[i].y *= d; r[i].z *= d; r[i].w *= d;
        s.x += r[i].x; s.y += r[i].y; s.z += r[i].z; s.w += r[i].w;
    }
    red[sg][qi] = s;
    __syncthreads();

    // exclusive prefix over earlier subgroups of this chunk
    float4 acc = base;
    for (int k = 0; k < sg; ++k) {
        float4 p = red[k][qi];
        acc.x += p.x; acc.y += p.y; acc.z += p.z; acc.w += p.w;
    }

    // replay from registers, apply per-step normalization, float4 store
    float* op = out + rowbase + (size_t)(t0 + sg * SPS_) * DIM_ + q;
#pragma unroll
    for (int i = 0; i < SPS_; ++i) {
        float4 cc = cof[sg * SPS_ + i];
        float f = ou ? cc.w : cc.z;
        acc.x += r[i].x; acc.y += r[i].y; acc.z += r[i].z; acc.w += r[i].w;
        float4 o = make_float4(acc.x * f, acc.y * f, acc.z * f, acc.w * f);
        *(float4*)(op + (size_t)i * DIM_) = o;
    }
}

// ---------------------------------------------------------------------------
extern "C" void kernel_launch(void* const* d_in, const int* in_sizes, int n_in,
                              void* d_out, int out_size, void* d_ws, size_t ws_size,
                              hipStream_t stream) {
    const float* ts    = (const float*)d_in[0];   // [B,T,1] fp32
    const float* noise = (const float*)d_in[1];   // [B,T,DIM] fp32
    float* out = (float*)d_out;                   // [B,T,DIM] fp32
    // NOTE: d_ws deliberately untouched — touching it costs a 512 MiB
    // re-poison fill (~80 us) per iteration. Partials live inside `out`.
    (void)d_ws; (void)ws_size; (void)in_sizes; (void)n_in; (void)out_size;

    partial_kernel<<<B_ * NC_, 256, 0, stream>>>(ts, noise, out);
    prefix_kernel <<<B_,       64,  0, stream>>>(out);
    scan_kernel   <<<B_ * NC_, 256, 0, stream>>>(ts, noise, out);
}